// Round 9
// baseline (255.196 us; speedup 1.0000x reference)
//
#include <hip/hip_runtime.h>
#include <hip/hip_bf16.h>
#include <math.h>

#define EMBD 768
#define FFN_HID 2048
#define HEAD_DIM 64
#define KV_H 5
#define KV_DIM 320
#define Q_H 15
#define QDIM (Q_H * HEAD_DIM) /* 960 */
#define BB 4
#define LL 512
#define LC 2048
#define EPSV 1.1920929e-07f

typedef __attribute__((ext_vector_type(8))) __bf16 bf16x8;
typedef __attribute__((ext_vector_type(2))) __bf16 bf16x2;
typedef __attribute__((ext_vector_type(8))) short short8;
typedef __attribute__((ext_vector_type(4))) float floatx4;
typedef __attribute__((ext_vector_type(2))) unsigned uint2v;
typedef unsigned short ushort;

// 0.125 (1/sqrt(64)) * log2(e), folded into q at projection time
#define RSCALE 0.18033688011112042f

__device__ inline ushort f2bf(float f) {
  union { float f; unsigned u; } c; c.f = f;
  return (ushort)((c.u + 0x8000u) >> 16);
}
__device__ inline float bf2f(ushort s) {
  union { unsigned u; float f; } c; c.u = ((unsigned)s) << 16;
  return c.f;
}
// pack two fp32 -> two bf16 in one u32 (HW packed convert when available)
#if __has_builtin(__builtin_amdgcn_cvt_pk_bf16_f32)
__device__ inline unsigned pk2bf(float a, float b) {
  union { bf16x2 v; unsigned u; } c;
  c.v = __builtin_amdgcn_cvt_pk_bf16_f32(a, b);
  return c.u;
}
#else
__device__ inline unsigned pk2bf(float a, float b) {
  union { float f; unsigned u; } x, y; x.f = a; y.f = b;
  return ((x.u + 0x8000u) >> 16) | ((y.u + 0x8000u) & 0xffff0000u);
}
#endif

__device__ __forceinline__ void glds16(const ushort* g, ushort* l) {
  __builtin_amdgcn_global_load_lds(
      (const __attribute__((address_space(1))) unsigned int*)g,
      (__attribute__((address_space(3))) unsigned int*)l, 16, 0, 0);
}

// ---------------- RMSNorm fp32 in -> bf16 out ----------------
__global__ __launch_bounds__(256) void rmsnorm_kernel(const float* __restrict__ x,
                                                      const float* __restrict__ w,
                                                      ushort* __restrict__ out) {
  int row = blockIdx.x;
  const float* xr = x + (size_t)row * EMBD;
  ushort* orow = out + (size_t)row * EMBD;
  int tid = threadIdx.x;
  float ss = 0.f;
  for (int i = tid; i < EMBD; i += 256) { float v = xr[i]; ss += v * v; }
  for (int off = 32; off > 0; off >>= 1) ss += __shfl_down(ss, off, 64);
  __shared__ float sred[4];
  if ((tid & 63) == 0) sred[tid >> 6] = ss;
  __syncthreads();
  float tot = sred[0] + sred[1] + sred[2] + sred[3];
  float scale = rsqrtf(tot * (1.0f / EMBD) + EPSV);
  for (int i = tid; i < EMBD; i += 256) orow[i] = f2bf(xr[i] * scale * w[i]);
}

// ---------------- merged weight transposes ----------------
struct TD { const float* W; ushort* Wt; int K; int N; int nx; int base; };
struct TD7 { TD d[7]; };

__global__ __launch_bounds__(256) void transpose_all(TD7 ds, int ntot) {
  int bid = blockIdx.x;
  int sel = 0;
#pragma unroll
  for (int j = 1; j < 7; ++j) sel = (bid >= ds.d[j].base) ? j : sel;
  TD t = ds.d[sel];
  int rel = bid - t.base;
  int bx = rel % t.nx, by = rel / t.nx;
  int k0 = by * 64, n0 = bx * 64;
  __shared__ ushort T[64][72];
  int tid = threadIdx.x;
  int r = tid >> 2, cb = (tid & 3) * 16;
#pragma unroll
  for (int i = 0; i < 16; i += 4) {
    float4 f = *(const float4*)(t.W + (size_t)(k0 + r) * t.N + n0 + cb + i);
    T[r][cb + i + 0] = f2bf(f.x); T[r][cb + i + 1] = f2bf(f.y);
    T[r][cb + i + 2] = f2bf(f.z); T[r][cb + i + 3] = f2bf(f.w);
  }
  __syncthreads();
#pragma unroll
  for (int i = 0; i < 2; ++i) {
    short8 v;
#pragma unroll
    for (int j = 0; j < 8; ++j) v[j] = (short)T[cb + i * 8 + j][r];
    *(short8*)(t.Wt + (size_t)(n0 + r) * t.K + k0 + cb + i * 8) = v;
  }
}

// ---------------- fp32 -> bf16 convert for text_k + text_v ----------------
__global__ __launch_bounds__(256) void conv_f2b(const float* __restrict__ ka,
                                                const float* __restrict__ va,
                                                ushort* __restrict__ ko,
                                                ushort* __restrict__ vo, int n4each) {
  int i = blockIdx.x * 256 + threadIdx.x;
  const float* src = (i < n4each) ? ka : va;
  ushort* dst = (i < n4each) ? ko : vo;
  int j = (i < n4each) ? i : i - n4each;
  float4 f = *(const float4*)(src + (size_t)j * 4);
  ushort* o = dst + (size_t)j * 4;
  o[0] = f2bf(f.x); o[1] = f2bf(f.y); o[2] = f2bf(f.z); o[3] = f2bf(f.w);
}

// ============ 128x64-tile bf16 GEMM, split-K, fp32 atomicAdd epilogue ============
// C (fp32, pre-seeded with residual) += A[M,K] @ Bt[N,K]^T over k in [klo,khi)
__global__ __launch_bounds__(256) void gemm128_atomic(const ushort* __restrict__ A,
                                                      const ushort* __restrict__ Bt,
                                                      float* __restrict__ C,
                                                      int M, int N, int K,
                                                      int ksplit) {
  __shared__ ushort As[128 * 64];
  __shared__ ushort Bs[64 * 64];
  int klo = blockIdx.z * ksplit;
  int khi = min(K, klo + ksplit);
  int tid = threadIdx.x;
  int w = tid >> 6, lane = tid & 63;
  int lm = lane & 15, lq = lane >> 4;
  int m0 = blockIdx.y * 128, n0 = blockIdx.x * 64;
  int wm = (w & 1) * 64, wn = (w >> 1) * 32;
  int arow = lane >> 3, acol = ((lane & 7) ^ arow) << 3;
  int kg[2] = {((lq) ^ (lm & 7)) << 3, ((4 + lq) ^ (lm & 7)) << 3};
  floatx4 acc[4][2];
#pragma unroll
  for (int i = 0; i < 4; ++i)
#pragma unroll
    for (int j = 0; j < 2; ++j) acc[i][j] = (floatx4){0.f, 0.f, 0.f, 0.f};
  for (int k0 = klo; k0 < khi; k0 += 64) {
#pragma unroll
    for (int s = 0; s < 4; ++s) {
      int g = (w << 2) + s;
      glds16(A + (size_t)(m0 + g * 8 + arow) * K + k0 + acol, &As[g * 512]);
    }
#pragma unroll
    for (int s = 0; s < 2; ++s) {
      int g = (w << 1) + s;
      glds16(Bt + (size_t)(n0 + g * 8 + arow) * K + k0 + acol, &Bs[g * 512]);
    }
    __syncthreads();
#pragma unroll
    for (int kc = 0; kc < 2; ++kc) {
      bf16x8 af[4], bf[2];
#pragma unroll
      for (int mt = 0; mt < 4; ++mt)
        af[mt] = *(const bf16x8*)&As[(wm + mt * 16 + lm) * 64 + kg[kc]];
#pragma unroll
      for (int nt = 0; nt < 2; ++nt)
        bf[nt] = *(const bf16x8*)&Bs[(wn + nt * 16 + lm) * 64 + kg[kc]];
#pragma unroll
      for (int mt = 0; mt < 4; ++mt)
#pragma unroll
        for (int nt = 0; nt < 2; ++nt)
          acc[mt][nt] = __builtin_amdgcn_mfma_f32_16x16x32_bf16(af[mt], bf[nt], acc[mt][nt], 0, 0, 0);
    }
    __syncthreads();
  }
#pragma unroll
  for (int mt = 0; mt < 4; ++mt)
#pragma unroll
    for (int nt = 0; nt < 2; ++nt)
#pragma unroll
      for (int r = 0; r < 4; ++r) {
        int row = m0 + wm + mt * 16 + lq * 4 + r;
        int col = n0 + wn + nt * 16 + lm;
        atomicAdd(&C[(size_t)row * N + col], acc[mt][nt][r]);
      }
}

// ---- z-merged k/v projection, 128x64 tiles; V written pre-transposed ----
__global__ __launch_bounds__(256) void gemm_kv128(const ushort* __restrict__ Ak,
                                                  const ushort* __restrict__ Av,
                                                  const ushort* __restrict__ Btk,
                                                  const ushort* __restrict__ Btv,
                                                  ushort* __restrict__ Ck,
                                                  ushort* __restrict__ Vt,
                                                  int M, int N, int K) {
  const ushort* A = blockIdx.z ? Av : Ak;
  const ushort* Bt = blockIdx.z ? Btv : Btk;
  __shared__ ushort As[128 * 64];
  __shared__ ushort Bs[64 * 64];
  int tid = threadIdx.x;
  int w = tid >> 6, lane = tid & 63;
  int lm = lane & 15, lq = lane >> 4;
  int m0 = blockIdx.y * 128, n0 = blockIdx.x * 64;
  int wm = (w & 1) * 64, wn = (w >> 1) * 32;
  int arow = lane >> 3, acol = ((lane & 7) ^ arow) << 3;
  int kg[2] = {((lq) ^ (lm & 7)) << 3, ((4 + lq) ^ (lm & 7)) << 3};
  floatx4 acc[4][2];
#pragma unroll
  for (int i = 0; i < 4; ++i)
#pragma unroll
    for (int j = 0; j < 2; ++j) acc[i][j] = (floatx4){0.f, 0.f, 0.f, 0.f};
  for (int k0 = 0; k0 < K; k0 += 64) {
#pragma unroll
    for (int s = 0; s < 4; ++s) {
      int g = (w << 2) + s;
      glds16(A + (size_t)(m0 + g * 8 + arow) * K + k0 + acol, &As[g * 512]);
    }
#pragma unroll
    for (int s = 0; s < 2; ++s) {
      int g = (w << 1) + s;
      glds16(Bt + (size_t)(n0 + g * 8 + arow) * K + k0 + acol, &Bs[g * 512]);
    }
    __syncthreads();
#pragma unroll
    for (int kc = 0; kc < 2; ++kc) {
      bf16x8 af[4], bf[2];
#pragma unroll
      for (int mt = 0; mt < 4; ++mt)
        af[mt] = *(const bf16x8*)&As[(wm + mt * 16 + lm) * 64 + kg[kc]];
#pragma unroll
      for (int nt = 0; nt < 2; ++nt)
        bf[nt] = *(const bf16x8*)&Bs[(wn + nt * 16 + lm) * 64 + kg[kc]];
#pragma unroll
      for (int mt = 0; mt < 4; ++mt)
#pragma unroll
        for (int nt = 0; nt < 2; ++nt)
          acc[mt][nt] = __builtin_amdgcn_mfma_f32_16x16x32_bf16(af[mt], bf[nt], acc[mt][nt], 0, 0, 0);
    }
    __syncthreads();
  }
  if (blockIdx.z == 0) {  // K: row-major [token][KV_DIM]
#pragma unroll
    for (int mt = 0; mt < 4; ++mt)
#pragma unroll
      for (int nt = 0; nt < 2; ++nt)
#pragma unroll
        for (int r = 0; r < 4; ++r) {
          int row = m0 + wm + mt * 16 + lq * 4 + r;
          int col = n0 + wn + nt * 16 + lm;
          Ck[(size_t)row * N + col] = f2bf(acc[mt][nt][r]);
        }
  } else {  // V: write transposed vt[(b*5+kvh)*64+d][token], 4 tokens packed
    int kvh = n0 >> 6;
#pragma unroll
    for (int mt = 0; mt < 4; ++mt)
#pragma unroll
      for (int nt = 0; nt < 2; ++nt) {
        int d = wn + nt * 16 + lm;
        int grow = m0 + wm + mt * 16 + lq * 4;  // token base, 4-aligned
        int b = grow >> 11;
        int tok = grow & (LC - 1);
        size_t a = ((size_t)(b * KV_H + kvh) * 64 + d) * LC + tok;
        uint2v pk = (uint2v){pk2bf(acc[mt][nt][0], acc[mt][nt][1]),
                             pk2bf(acc[mt][nt][2], acc[mt][nt][3])};
        *(uint2v*)&Vt[a] = pk;
      }
  }
}

// ---- q projection, 128x64 tiles, fused RoPE + softmax prescale ----
__global__ __launch_bounds__(256) void gemm_q_rope(const ushort* __restrict__ A,
                                                   const ushort* __restrict__ Bt,
                                                   ushort* __restrict__ Q,
                                                   int M, int N, int K) {
  __shared__ ushort As[128 * 64];
  __shared__ ushort Bs[64 * 64];
  int tid = threadIdx.x;
  int w = tid >> 6, lane = tid & 63;
  int lm = lane & 15, lq = lane >> 4;
  int m0 = blockIdx.y * 128, n0 = blockIdx.x * 64;
  int wm = (w & 1) * 64, wn = (w >> 1) * 16;  // cols wn+lm and +32
  int arow = lane >> 3, acol = ((lane & 7) ^ arow) << 3;
  int kg[2] = {((lq) ^ (lm & 7)) << 3, ((4 + lq) ^ (lm & 7)) << 3};
  floatx4 acc[4][2];
#pragma unroll
  for (int i = 0; i < 4; ++i)
#pragma unroll
    for (int j = 0; j < 2; ++j) acc[i][j] = (floatx4){0.f, 0.f, 0.f, 0.f};
  for (int k0 = 0; k0 < K; k0 += 64) {
#pragma unroll
    for (int s = 0; s < 4; ++s) {
      int g = (w << 2) + s;
      glds16(A + (size_t)(m0 + g * 8 + arow) * K + k0 + acol, &As[g * 512]);
    }
#pragma unroll
    for (int s = 0; s < 2; ++s) {
      int g = (w << 1) + s;
      glds16(Bt + (size_t)(n0 + g * 8 + arow) * K + k0 + acol, &Bs[g * 512]);
    }
    __syncthreads();
#pragma unroll
    for (int kc = 0; kc < 2; ++kc) {
      bf16x8 af[4], bf[2];
#pragma unroll
      for (int mt = 0; mt < 4; ++mt)
        af[mt] = *(const bf16x8*)&As[(wm + mt * 16 + lm) * 64 + kg[kc]];
#pragma unroll
      for (int nt = 0; nt < 2; ++nt) {
        int br = wn + nt * 32 + lm;
        bf[nt] = *(const bf16x8*)&Bs[br * 64 + (((kc * 4 + lq) ^ (br & 7)) << 3)];
      }
#pragma unroll
      for (int mt = 0; mt < 4; ++mt)
#pragma unroll
        for (int nt = 0; nt < 2; ++nt)
          acc[mt][nt] = __builtin_amdgcn_mfma_f32_16x16x32_bf16(af[mt], bf[nt], acc[mt][nt], 0, 0, 0);
    }
    __syncthreads();
  }
  int d = wn + lm;  // 0..31
  float invts = exp2f(-(float)d * 0.4152410118609203f);  // 10000^(-d/32)
#pragma unroll
  for (int mt = 0; mt < 4; ++mt)
#pragma unroll
    for (int r = 0; r < 4; ++r) {
      int row = m0 + wm + mt * 16 + lq * 4 + r;
      int l = row & (LL - 1);
      float th = (float)l * invts;
      float s, c;
      __sincosf(th, &s, &c);
      float q1 = acc[mt][0][r], q2 = acc[mt][1][r];
      size_t base = (size_t)row * N + n0 + d;
      Q[base] = f2bf((q1 * c - q2 * s) * RSCALE);
      Q[base + 32] = f2bf((q2 * c + q1 * s) * RSCALE);
    }
}

// ---- fused gate+up: 128x64 tile, silu(g)*u epilogue ----
__global__ __launch_bounds__(256) void gemm_gateup(const ushort* __restrict__ A,
                                                   const ushort* __restrict__ Bg,
                                                   const ushort* __restrict__ Bu,
                                                   ushort* __restrict__ H,
                                                   int M, int N, int K) {
  __shared__ ushort As[128 * 64];
  __shared__ ushort Bs0[64 * 64];
  __shared__ ushort Bs1[64 * 64];
  int tid = threadIdx.x;
  int w = tid >> 6, lane = tid & 63;
  int lm = lane & 15, lq = lane >> 4;
  int m0 = blockIdx.y * 128, n0 = blockIdx.x * 64;
  int wm = (w & 1) * 64, wn = (w >> 1) * 32;
  int arow = lane >> 3, acol = ((lane & 7) ^ arow) << 3;
  int kg[2] = {((lq) ^ (lm & 7)) << 3, ((4 + lq) ^ (lm & 7)) << 3};
  floatx4 accg[4][2], accu[4][2];
#pragma unroll
  for (int i = 0; i < 4; ++i)
#pragma unroll
    for (int j = 0; j < 2; ++j) {
      accg[i][j] = (floatx4){0.f, 0.f, 0.f, 0.f};
      accu[i][j] = (floatx4){0.f, 0.f, 0.f, 0.f};
    }
  for (int k0 = 0; k0 < K; k0 += 64) {
#pragma unroll
    for (int s = 0; s < 4; ++s) {
      int g = (w << 2) + s;
      glds16(A + (size_t)(m0 + g * 8 + arow) * K + k0 + acol, &As[g * 512]);
    }
#pragma unroll
    for (int s = 0; s < 2; ++s) {
      int g = (w << 1) + s;
      glds16(Bg + (size_t)(n0 + g * 8 + arow) * K + k0 + acol, &Bs0[g * 512]);
      glds16(Bu + (size_t)(n0 + g * 8 + arow) * K + k0 + acol, &Bs1[g * 512]);
    }
    __syncthreads();
#pragma unroll
    for (int kc = 0; kc < 2; ++kc) {
      bf16x8 af[4], bg[2], bu[2];
#pragma unroll
      for (int mt = 0; mt < 4; ++mt)
        af[mt] = *(const bf16x8*)&As[(wm + mt * 16 + lm) * 64 + kg[kc]];
#pragma unroll
      for (int nt = 0; nt < 2; ++nt) {
        bg[nt] = *(const bf16x8*)&Bs0[(wn + nt * 16 + lm) * 64 + kg[kc]];
        bu[nt] = *(const bf16x8*)&Bs1[(wn + nt * 16 + lm) * 64 + kg[kc]];
      }
#pragma unroll
      for (int mt = 0; mt < 4; ++mt)
#pragma unroll
        for (int nt = 0; nt < 2; ++nt) {
          accg[mt][nt] = __builtin_amdgcn_mfma_f32_16x16x32_bf16(af[mt], bg[nt], accg[mt][nt], 0, 0, 0);
          accu[mt][nt] = __builtin_amdgcn_mfma_f32_16x16x32_bf16(af[mt], bu[nt], accu[mt][nt], 0, 0, 0);
        }
    }
    __syncthreads();
  }
#pragma unroll
  for (int mt = 0; mt < 4; ++mt)
#pragma unroll
    for (int nt = 0; nt < 2; ++nt)
#pragma unroll
      for (int r = 0; r < 4; ++r) {
        int row = m0 + wm + mt * 16 + lq * 4 + r;
        int col = n0 + wn + nt * 16 + lm;
        float gv = accg[mt][nt][r];
        float hv = gv / (1.f + __expf(-gv)) * accu[mt][nt][r];
        H[(size_t)row * N + col] = f2bf(hv);
      }
}

// ============ MFMA flash attention: 64-key tiles, S^T trick, split-Lc x2 ============
__global__ __launch_bounds__(256) void attn_kernel(const ushort* __restrict__ qb,
                                                   const ushort* __restrict__ kb,
                                                   const ushort* __restrict__ vt,
                                                   ushort* __restrict__ Op,
                                                   float* __restrict__ Ml) {
  int bx = blockIdx.x, h = blockIdx.y, b = blockIdx.z;
  int lt = bx & 7, sp = bx >> 3;
  int kvh = h / 3;
  int l0 = lt * 64;
  int kv0 = sp * 1024;
  __shared__ ushort Qs[64 * 64];
  __shared__ ushort Ks[64 * 64];
  __shared__ ushort Vs[64 * 64];
  __shared__ ushort Ps[4][16][72];
  int tid = threadIdx.x;
  int w = tid >> 6, lane = tid & 63, lm = lane & 15, lq = lane >> 4;
  int arow = lane >> 3, acol = ((lane & 7) ^ arow) << 3;
  int kg[2] = {((lq) ^ (lm & 7)) << 3, ((4 + lq) ^ (lm & 7)) << 3};
#pragma unroll
  for (int s = 0; s < 2; ++s) {
    int g = (w << 1) + s;
    glds16(qb + (size_t)(b * LL + l0 + g * 8 + arow) * QDIM + h * HEAD_DIM + acol, &Qs[g * 512]);
  }
  __syncthreads();
  bf16x8 aq[2];
  {
    int qr = w * 16 + lm;
    aq[0] = *(const bf16x8*)&Qs[qr * 64 + (((lq) ^ (qr & 7)) << 3)];
    aq[1] = *(const bf16x8*)&Qs[qr * 64 + (((4 + lq) ^ (qr & 7)) << 3)];
  }
  floatx4 oacc[4];
#pragma unroll
  for (int i = 0; i < 4; ++i) oacc[i] = (floatx4){0.f, 0.f, 0.f, 0.f};
  float l_loc = 0.f;

  for (int m0 = kv0; m0 < kv0 + 1024; m0 += 64) {
#pragma unroll
    for (int s = 0; s < 2; ++s) {
      int g = (w << 1) + s;
      glds16(kb + (size_t)(b * LC + m0 + g * 8 + arow) * KV_DIM + kvh * HEAD_DIM + acol, &Ks[g * 512]);
      glds16(vt + ((size_t)(b * KV_H + kvh) * 64 + g * 8 + arow) * LC + m0 + acol, &Vs[g * 512]);
    }
    __syncthreads();

    floatx4 sacc[4];
#pragma unroll
    for (int nt = 0; nt < 4; ++nt) sacc[nt] = (floatx4){0.f, 0.f, 0.f, 0.f};
#pragma unroll
    for (int kc = 0; kc < 2; ++kc) {
#pragma unroll
      for (int nt = 0; nt < 4; ++nt) {
        bf16x8 bk = *(const bf16x8*)&Ks[(nt * 16 + lm) * 64 + kg[kc]];
        sacc[nt] = __builtin_amdgcn_mfma_f32_16x16x32_bf16(bk, aq[kc], sacc[nt], 0, 0, 0);
      }
    }
#pragma unroll
    for (int nt = 0; nt < 4; ++nt) {
      float p0 = exp2f(sacc[nt][0]);
      float p1 = exp2f(sacc[nt][1]);
      float p2 = exp2f(sacc[nt][2]);
      float p3 = exp2f(sacc[nt][3]);
      l_loc += (p0 + p1) + (p2 + p3);
      uint2v pk = (uint2v){pk2bf(p0, p1), pk2bf(p2, p3)};
      *(uint2v*)&Ps[w][lm][nt * 16 + lq * 4] = pk;
    }
#pragma unroll
    for (int kc2 = 0; kc2 < 2; ++kc2) {
      bf16x8 ap = *(const bf16x8*)&Ps[w][lm][kc2 * 32 + lq * 8];
#pragma unroll
      for (int dt = 0; dt < 4; ++dt) {
        bf16x8 bv = *(const bf16x8*)&Vs[(dt * 16 + lm) * 64 + kg[kc2]];
        oacc[dt] = __builtin_amdgcn_mfma_f32_16x16x32_bf16(ap, bv, oacc[dt], 0, 0, 0);
      }
    }
    __syncthreads();
  }
  l_loc += __shfl_xor(l_loc, 16);
  l_loc += __shfl_xor(l_loc, 32);
#pragma unroll
  for (int r = 0; r < 4; ++r) {
    int row = l0 + w * 16 + lq * 4 + r;
    size_t base = ((size_t)sp * (BB * LL) + b * LL + row) * QDIM + h * HEAD_DIM;
#pragma unroll
    for (int dt = 0; dt < 4; ++dt) Op[base + dt * 16 + lm] = f2bf(oacc[dt][r]);
  }
  if (lq == 0) {
    int row = l0 + w * 16 + lm;
    Ml[((size_t)sp * (BB * LL) + b * LL + row) * Q_H + h] = l_loc;
  }
}

// combine two split partials -> ctx
__global__ __launch_bounds__(256) void combine_kernel(ushort* __restrict__ Op,
                                                      const float* __restrict__ Ml,
                                                      ushort* __restrict__ ctx) {
  int bl = blockIdx.x, t = threadIdx.x;
  if (t >= 240) return;
  int h = t >> 4, d4 = (t & 15) * 4;
  float la = Ml[(size_t)bl * Q_H + h];
  float lb = Ml[((size_t)(BB * LL) + bl) * Q_H + h];
  float inv = 1.f / (la + lb);
  size_t i0 = (size_t)bl * QDIM + h * HEAD_DIM + d4;
  size_t i1 = (size_t)(BB * LL) * QDIM + i0;
#pragma unroll
  for (int j = 0; j < 4; ++j) {
    float o = (bf2f(Op[i0 + j]) + bf2f(Op[i1 + j])) * inv;
    ctx[i0 + j] = f2bf(o);
  }
}

extern "C" void kernel_launch(void* const* d_in, const int* in_sizes, int n_in,
                              void* d_out, int out_size, void* d_ws, size_t ws_size,
                              hipStream_t stream) {
  const float* x      = (const float*)d_in[0];
  const float* text_k = (const float*)d_in[1];
  const float* text_v = (const float*)d_in[2];
  const float* ln1_w  = (const float*)d_in[3];
  const float* ln2_w  = (const float*)d_in[4];
  const float* wq     = (const float*)d_in[5];
  const float* wk     = (const float*)d_in[6];
  const float* wv     = (const float*)d_in[7];
  const float* wo     = (const float*)d_in[8];
  const float* w_gate = (const float*)d_in[9];
  const float* w_up   = (const float*)d_in[10];
  const float* w_down = (const float*)d_in[11];
  float* out = (float*)d_out;
  char* base = (char*)d_ws;

  const int BL = BB * LL;   // 2048
  const int BLC = BB * LC;  // 8192

  ushort* xnorm = (ushort*)(base + 0);          // 3,145,728
  ushort* wqt   = (ushort*)(base + 3145728);    // 1,474,560
  ushort* wkt   = (ushort*)(base + 4620288);    //   204,800
  ushort* wvt   = (ushort*)(base + 4825088);    //   204,800
  ushort* wot   = (ushort*)(base + 5029888);    // 1,474,560
  ushort* wgt   = (ushort*)(base + 6504448);    // 3,145,728
  ushort* wut   = (ushort*)(base + 9650176);    // 3,145,728
  ushort* wdt   = (ushort*)(base + 12795904);   // 3,145,728
  ushort* kbuf  = (ushort*)(base + 15941632);   // 5,242,880
  ushort* vtb   = (ushort*)(base + 21184512);   // 5,242,880
  float*  x2    = (float*) (base + 26427392);   // 6,291,456
  ushort* qb    = (ushort*)(base + 32718848);   // 3,932,160
  float*  Ml    = (float*) (base + 36651008);   //   245,760 (+pad)
  ushort* tkb   = (ushort*)(base + 37142528);   // 5,242,880 (bf16 text_k)
  ushort* tvb   = (ushort*)(base + 42385408);   // 5,242,880 (bf16 text_v)
  char* SCR = base + 47628288;
  ushort* Op    = (ushort*)SCR;                 // 2 x 3,932,160
  ushort* ctxb  = (ushort*)SCR;                 // combine out, in-place over Op0
  ushort* gbuf  = (ushort*)(base + 15941632);   // alias kbuf+vtb (dead after attn)

  TD7 ds;
  ds.d[0] = {wq,     wqt, EMBD,    QDIM,    QDIM / 64,    0};
  ds.d[1] = {wk,     wkt, KV_DIM,  KV_DIM,  KV_DIM / 64,  180};
  ds.d[2] = {wv,     wvt, KV_DIM,  KV_DIM,  KV_DIM / 64,  205};
  ds.d[3] = {wo,     wot, QDIM,    EMBD,    EMBD / 64,    230};
  ds.d[4] = {w_gate, wgt, EMBD,    FFN_HID, FFN_HID / 64, 410};
  ds.d[5] = {w_up,   wut, EMBD,    FFN_HID, FFN_HID / 64, 794};
  ds.d[6] = {w_down, wdt, FFN_HID, EMBD,    EMBD / 64,    1178};
  const int ntrans = 1178 + (EMBD / 64) * (FFN_HID / 64);  // 1562
  transpose_all<<<ntrans, 256, 0, stream>>>(ds, ntrans);
  rmsnorm_kernel<<<BL, 256, 0, stream>>>(x, ln1_w, xnorm);
  conv_f2b<<<(2 * BLC * KV_DIM / 4) / 256, 256, 0, stream>>>(text_k, text_v, tkb, tvb, BLC * KV_DIM / 4);
  // seed x2 with residual x (fp32, 6.29 MB)
  hipMemcpyAsync(x2, x, (size_t)BL * EMBD * sizeof(float), hipMemcpyDeviceToDevice, stream);

  // k/v projections, 128-tile; V written pre-transposed
  gemm_kv128<<<dim3(KV_DIM / 64, BLC / 128, 2), 256, 0, stream>>>(tkb, tvb, wkt, wvt, kbuf, vtb, BLC, KV_DIM, KV_DIM);

  // q projection + fused rope
  gemm_q_rope<<<dim3(QDIM / 64, BL / 128), 256, 0, stream>>>(xnorm, wqt, qb, BL, QDIM, EMBD);

  attn_kernel<<<dim3(16, Q_H, BB), 256, 0, stream>>>(qb, kbuf, vtb, Op, Ml);
  combine_kernel<<<BL, 256, 0, stream>>>(Op, Ml, ctxb);

  // x2 += ctx @ wo  (split-K2, atomic)
  gemm128_atomic<<<dim3(EMBD / 64, BL / 128, 2), 256, 0, stream>>>(ctxb, wot, x2, BL, EMBD, QDIM, 448);

  rmsnorm_kernel<<<BL, 256, 0, stream>>>(x2, ln2_w, xnorm);
  // seed out with x2 (residual for down-proj)
  hipMemcpyAsync(out, x2, (size_t)BL * EMBD * sizeof(float), hipMemcpyDeviceToDevice, stream);

  gemm_gateup<<<dim3(FFN_HID / 64, BL / 128), 256, 0, stream>>>(xnorm, wgt, wut, gbuf, BL, FFN_HID, EMBD);
  // out += h @ w_down  (split-K2, atomic)
  gemm128_atomic<<<dim3(EMBD / 64, BL / 128, 2), 256, 0, stream>>>(gbuf, wdt, out, BL, EMBD, FFN_HID, 1024);
}

// Round 10
// 241.689 us; speedup vs baseline: 1.0559x; 1.0559x over previous
//
#include <hip/hip_runtime.h>
#include <hip/hip_bf16.h>
#include <math.h>

#define EMBD 768
#define FFN_HID 2048
#define HEAD_DIM 64
#define KV_H 5
#define KV_DIM 320
#define Q_H 15
#define QDIM (Q_H * HEAD_DIM) /* 960 */
#define BB 4
#define LL 512
#define LC 2048
#define EPSV 1.1920929e-07f

typedef __attribute__((ext_vector_type(8))) __bf16 bf16x8;
typedef __attribute__((ext_vector_type(2))) __bf16 bf16x2;
typedef __attribute__((ext_vector_type(8))) short short8;
typedef __attribute__((ext_vector_type(4))) float floatx4;
typedef __attribute__((ext_vector_type(2))) unsigned uint2v;
typedef unsigned short ushort;

// 0.125 (1/sqrt(64)) * log2(e), folded into q at projection time
#define RSCALE 0.18033688011112042f

__device__ inline ushort f2bf(float f) {
  union { float f; unsigned u; } c; c.f = f;
  return (ushort)((c.u + 0x8000u) >> 16);
}
__device__ inline float bf2f(ushort s) {
  union { unsigned u; float f; } c; c.u = ((unsigned)s) << 16;
  return c.f;
}
#if __has_builtin(__builtin_amdgcn_cvt_pk_bf16_f32)
__device__ inline unsigned pk2bf(float a, float b) {
  union { bf16x2 v; unsigned u; } c;
  c.v = __builtin_amdgcn_cvt_pk_bf16_f32(a, b);
  return c.u;
}
#else
__device__ inline unsigned pk2bf(float a, float b) {
  union { float f; unsigned u; } x, y; x.f = a; y.f = b;
  return ((x.u + 0x8000u) >> 16) | ((y.u + 0x8000u) & 0xffff0000u);
}
#endif

__device__ __forceinline__ void glds16(const ushort* g, ushort* l) {
  __builtin_amdgcn_global_load_lds(
      (const __attribute__((address_space(1))) unsigned int*)g,
      (__attribute__((address_space(3))) unsigned int*)l, 16, 0, 0);
}

// ---------------- RMSNorm fp32 in -> bf16 out ----------------
__global__ __launch_bounds__(256) void rmsnorm_kernel(const float* __restrict__ x,
                                                      const float* __restrict__ w,
                                                      ushort* __restrict__ out) {
  int row = blockIdx.x;
  const float* xr = x + (size_t)row * EMBD;
  ushort* orow = out + (size_t)row * EMBD;
  int tid = threadIdx.x;
  float ss = 0.f;
  for (int i = tid; i < EMBD; i += 256) { float v = xr[i]; ss += v * v; }
  for (int off = 32; off > 0; off >>= 1) ss += __shfl_down(ss, off, 64);
  __shared__ float sred[4];
  if ((tid & 63) == 0) sred[tid >> 6] = ss;
  __syncthreads();
  float tot = sred[0] + sred[1] + sred[2] + sred[3];
  float scale = rsqrtf(tot * (1.0f / EMBD) + EPSV);
  for (int i = tid; i < EMBD; i += 256) orow[i] = f2bf(xr[i] * scale * w[i]);
}

// ---------------- merged weight transposes ----------------
struct TD { const float* W; ushort* Wt; int K; int N; int nx; int base; };
struct TD7 { TD d[7]; };

__global__ __launch_bounds__(256) void transpose_all(TD7 ds, int ntot) {
  int bid = blockIdx.x;
  int sel = 0;
#pragma unroll
  for (int j = 1; j < 7; ++j) sel = (bid >= ds.d[j].base) ? j : sel;
  TD t = ds.d[sel];
  int rel = bid - t.base;
  int bx = rel % t.nx, by = rel / t.nx;
  int k0 = by * 64, n0 = bx * 64;
  __shared__ ushort T[64][72];
  int tid = threadIdx.x;
  int r = tid >> 2, cb = (tid & 3) * 16;
#pragma unroll
  for (int i = 0; i < 16; i += 4) {
    float4 f = *(const float4*)(t.W + (size_t)(k0 + r) * t.N + n0 + cb + i);
    T[r][cb + i + 0] = f2bf(f.x); T[r][cb + i + 1] = f2bf(f.y);
    T[r][cb + i + 2] = f2bf(f.z); T[r][cb + i + 3] = f2bf(f.w);
  }
  __syncthreads();
#pragma unroll
  for (int i = 0; i < 2; ++i) {
    short8 v;
#pragma unroll
    for (int j = 0; j < 8; ++j) v[j] = (short)T[cb + i * 8 + j][r];
    *(short8*)(t.Wt + (size_t)(n0 + r) * t.K + k0 + cb + i * 8) = v;
  }
}

// ---------------- fp32 -> bf16 convert for text_k + text_v ----------------
__global__ __launch_bounds__(256) void conv_f2b(const float* __restrict__ ka,
                                                const float* __restrict__ va,
                                                ushort* __restrict__ ko,
                                                ushort* __restrict__ vo, int n4each) {
  int i = blockIdx.x * 256 + threadIdx.x;
  const float* src = (i < n4each) ? ka : va;
  ushort* dst = (i < n4each) ? ko : vo;
  int j = (i < n4each) ? i : i - n4each;
  float4 f = *(const float4*)(src + (size_t)j * 4);
  ushort* o = dst + (size_t)j * 4;
  o[0] = f2bf(f.x); o[1] = f2bf(f.y); o[2] = f2bf(f.z); o[3] = f2bf(f.w);
}

// ============ 64x64-tile bf16 GEMM (4 waves 2x2), glds + swizzle ============
// OM: 1 = f32 out + residual Rf, 2 = bf16 out
template <int OM>
__global__ __launch_bounds__(256) void gemm64(const ushort* __restrict__ A,
                                              const ushort* __restrict__ Bt,
                                              const float* __restrict__ Rf,
                                              void* __restrict__ Cout,
                                              int M, int N, int K) {
  __shared__ ushort As[64 * 64];
  __shared__ ushort Bs[64 * 64];
  int tid = threadIdx.x;
  int w = tid >> 6, lane = tid & 63;
  int lm = lane & 15, lq = lane >> 4;
  int m0 = blockIdx.y * 64, n0 = blockIdx.x * 64;
  int wm = (w & 1) * 32, wn = (w >> 1) * 32;
  int arow = lane >> 3, acol = ((lane & 7) ^ arow) << 3;
  int kg[2] = {((lq) ^ (lm & 7)) << 3, ((4 + lq) ^ (lm & 7)) << 3};
  floatx4 acc[2][2];
#pragma unroll
  for (int i = 0; i < 2; ++i)
#pragma unroll
    for (int j = 0; j < 2; ++j) acc[i][j] = (floatx4){0.f, 0.f, 0.f, 0.f};
  for (int k0 = 0; k0 < K; k0 += 64) {
#pragma unroll
    for (int s = 0; s < 2; ++s) {
      int g = (w << 1) + s;
      glds16(A + (size_t)(m0 + g * 8 + arow) * K + k0 + acol, &As[g * 512]);
      glds16(Bt + (size_t)(n0 + g * 8 + arow) * K + k0 + acol, &Bs[g * 512]);
    }
    __syncthreads();
#pragma unroll
    for (int kc = 0; kc < 2; ++kc) {
      bf16x8 af[2], bf[2];
#pragma unroll
      for (int mt = 0; mt < 2; ++mt)
        af[mt] = *(const bf16x8*)&As[(wm + mt * 16 + lm) * 64 + kg[kc]];
#pragma unroll
      for (int nt = 0; nt < 2; ++nt)
        bf[nt] = *(const bf16x8*)&Bs[(wn + nt * 16 + lm) * 64 + kg[kc]];
#pragma unroll
      for (int mt = 0; mt < 2; ++mt)
#pragma unroll
        for (int nt = 0; nt < 2; ++nt)
          acc[mt][nt] = __builtin_amdgcn_mfma_f32_16x16x32_bf16(af[mt], bf[nt], acc[mt][nt], 0, 0, 0);
    }
    __syncthreads();
  }
#pragma unroll
  for (int mt = 0; mt < 2; ++mt)
#pragma unroll
    for (int nt = 0; nt < 2; ++nt)
#pragma unroll
      for (int r = 0; r < 4; ++r) {
        int row = m0 + wm + mt * 16 + lq * 4 + r;
        int col = n0 + wn + nt * 16 + lm;
        size_t idx = (size_t)row * N + col;
        float vv = acc[mt][nt][r];
        if (OM == 1) ((float*)Cout)[idx] = vv + Rf[idx];
        if (OM == 2) ((ushort*)Cout)[idx] = f2bf(vv);
      }
}

// ---- z-merged k/v projection, 128x64 tiles; V written pre-transposed ----
__global__ __launch_bounds__(256) void gemm_kv128(const ushort* __restrict__ Ak,
                                                  const ushort* __restrict__ Av,
                                                  const ushort* __restrict__ Btk,
                                                  const ushort* __restrict__ Btv,
                                                  ushort* __restrict__ Ck,
                                                  ushort* __restrict__ Vt,
                                                  int M, int N, int K) {
  const ushort* A = blockIdx.z ? Av : Ak;
  const ushort* Bt = blockIdx.z ? Btv : Btk;
  __shared__ ushort As[128 * 64];
  __shared__ ushort Bs[64 * 64];
  int tid = threadIdx.x;
  int w = tid >> 6, lane = tid & 63;
  int lm = lane & 15, lq = lane >> 4;
  int m0 = blockIdx.y * 128, n0 = blockIdx.x * 64;
  int wm = (w & 1) * 64, wn = (w >> 1) * 32;
  int arow = lane >> 3, acol = ((lane & 7) ^ arow) << 3;
  int kg[2] = {((lq) ^ (lm & 7)) << 3, ((4 + lq) ^ (lm & 7)) << 3};
  floatx4 acc[4][2];
#pragma unroll
  for (int i = 0; i < 4; ++i)
#pragma unroll
    for (int j = 0; j < 2; ++j) acc[i][j] = (floatx4){0.f, 0.f, 0.f, 0.f};
  for (int k0 = 0; k0 < K; k0 += 64) {
#pragma unroll
    for (int s = 0; s < 4; ++s) {
      int g = (w << 2) + s;
      glds16(A + (size_t)(m0 + g * 8 + arow) * K + k0 + acol, &As[g * 512]);
    }
#pragma unroll
    for (int s = 0; s < 2; ++s) {
      int g = (w << 1) + s;
      glds16(Bt + (size_t)(n0 + g * 8 + arow) * K + k0 + acol, &Bs[g * 512]);
    }
    __syncthreads();
#pragma unroll
    for (int kc = 0; kc < 2; ++kc) {
      bf16x8 af[4], bf[2];
#pragma unroll
      for (int mt = 0; mt < 4; ++mt)
        af[mt] = *(const bf16x8*)&As[(wm + mt * 16 + lm) * 64 + kg[kc]];
#pragma unroll
      for (int nt = 0; nt < 2; ++nt)
        bf[nt] = *(const bf16x8*)&Bs[(wn + nt * 16 + lm) * 64 + kg[kc]];
#pragma unroll
      for (int mt = 0; mt < 4; ++mt)
#pragma unroll
        for (int nt = 0; nt < 2; ++nt)
          acc[mt][nt] = __builtin_amdgcn_mfma_f32_16x16x32_bf16(af[mt], bf[nt], acc[mt][nt], 0, 0, 0);
    }
    __syncthreads();
  }
  if (blockIdx.z == 0) {  // K: row-major [token][KV_DIM]
#pragma unroll
    for (int mt = 0; mt < 4; ++mt)
#pragma unroll
      for (int nt = 0; nt < 2; ++nt)
#pragma unroll
        for (int r = 0; r < 4; ++r) {
          int row = m0 + wm + mt * 16 + lq * 4 + r;
          int col = n0 + wn + nt * 16 + lm;
          Ck[(size_t)row * N + col] = f2bf(acc[mt][nt][r]);
        }
  } else {  // V: write transposed vt[(b*5+kvh)*64+d][token], 4 tokens packed
    int kvh = n0 >> 6;
#pragma unroll
    for (int mt = 0; mt < 4; ++mt)
#pragma unroll
      for (int nt = 0; nt < 2; ++nt) {
        int d = wn + nt * 16 + lm;
        int grow = m0 + wm + mt * 16 + lq * 4;  // token base, 4-aligned
        int b = grow >> 11;
        int tok = grow & (LC - 1);
        size_t a = ((size_t)(b * KV_H + kvh) * 64 + d) * LC + tok;
        uint2v pk = (uint2v){pk2bf(acc[mt][nt][0], acc[mt][nt][1]),
                             pk2bf(acc[mt][nt][2], acc[mt][nt][3])};
        *(uint2v*)&Vt[a] = pk;
      }
  }
}

// ---- q projection, 128x64 tiles, fused RoPE + softmax prescale ----
__global__ __launch_bounds__(256) void gemm_q_rope(const ushort* __restrict__ A,
                                                   const ushort* __restrict__ Bt,
                                                   ushort* __restrict__ Q,
                                                   int M, int N, int K) {
  __shared__ ushort As[128 * 64];
  __shared__ ushort Bs[64 * 64];
  int tid = threadIdx.x;
  int w = tid >> 6, lane = tid & 63;
  int lm = lane & 15, lq = lane >> 4;
  int m0 = blockIdx.y * 128, n0 = blockIdx.x * 64;
  int wm = (w & 1) * 64, wn = (w >> 1) * 16;  // cols wn+lm and +32
  int arow = lane >> 3, acol = ((lane & 7) ^ arow) << 3;
  int kg[2] = {((lq) ^ (lm & 7)) << 3, ((4 + lq) ^ (lm & 7)) << 3};
  floatx4 acc[4][2];
#pragma unroll
  for (int i = 0; i < 4; ++i)
#pragma unroll
    for (int j = 0; j < 2; ++j) acc[i][j] = (floatx4){0.f, 0.f, 0.f, 0.f};
  for (int k0 = 0; k0 < K; k0 += 64) {
#pragma unroll
    for (int s = 0; s < 4; ++s) {
      int g = (w << 2) + s;
      glds16(A + (size_t)(m0 + g * 8 + arow) * K + k0 + acol, &As[g * 512]);
    }
#pragma unroll
    for (int s = 0; s < 2; ++s) {
      int g = (w << 1) + s;
      glds16(Bt + (size_t)(n0 + g * 8 + arow) * K + k0 + acol, &Bs[g * 512]);
    }
    __syncthreads();
#pragma unroll
    for (int kc = 0; kc < 2; ++kc) {
      bf16x8 af[4], bf[2];
#pragma unroll
      for (int mt = 0; mt < 4; ++mt)
        af[mt] = *(const bf16x8*)&As[(wm + mt * 16 + lm) * 64 + kg[kc]];
#pragma unroll
      for (int nt = 0; nt < 2; ++nt) {
        int br = wn + nt * 32 + lm;
        bf[nt] = *(const bf16x8*)&Bs[br * 64 + (((kc * 4 + lq) ^ (br & 7)) << 3)];
      }
#pragma unroll
      for (int mt = 0; mt < 4; ++mt)
#pragma unroll
        for (int nt = 0; nt < 2; ++nt)
          acc[mt][nt] = __builtin_amdgcn_mfma_f32_16x16x32_bf16(af[mt], bf[nt], acc[mt][nt], 0, 0, 0);
    }
    __syncthreads();
  }
  int d = wn + lm;  // 0..31
  float invts = exp2f(-(float)d * 0.4152410118609203f);  // 10000^(-d/32)
#pragma unroll
  for (int mt = 0; mt < 4; ++mt)
#pragma unroll
    for (int r = 0; r < 4; ++r) {
      int row = m0 + wm + mt * 16 + lq * 4 + r;
      int l = row & (LL - 1);
      float th = (float)l * invts;
      float s, c;
      __sincosf(th, &s, &c);
      float q1 = acc[mt][0][r], q2 = acc[mt][1][r];
      size_t base = (size_t)row * N + n0 + d;
      Q[base] = f2bf((q1 * c - q2 * s) * RSCALE);
      Q[base + 32] = f2bf((q2 * c + q1 * s) * RSCALE);
    }
}

// ---- fused gate+up: 128x64 tile, silu(g)*u epilogue ----
__global__ __launch_bounds__(256) void gemm_gateup(const ushort* __restrict__ A,
                                                   const ushort* __restrict__ Bg,
                                                   const ushort* __restrict__ Bu,
                                                   ushort* __restrict__ H,
                                                   int M, int N, int K) {
  __shared__ ushort As[128 * 64];
  __shared__ ushort Bs0[64 * 64];
  __shared__ ushort Bs1[64 * 64];
  int tid = threadIdx.x;
  int w = tid >> 6, lane = tid & 63;
  int lm = lane & 15, lq = lane >> 4;
  int m0 = blockIdx.y * 128, n0 = blockIdx.x * 64;
  int wm = (w & 1) * 64, wn = (w >> 1) * 32;
  int arow = lane >> 3, acol = ((lane & 7) ^ arow) << 3;
  int kg[2] = {((lq) ^ (lm & 7)) << 3, ((4 + lq) ^ (lm & 7)) << 3};
  floatx4 accg[4][2], accu[4][2];
#pragma unroll
  for (int i = 0; i < 4; ++i)
#pragma unroll
    for (int j = 0; j < 2; ++j) {
      accg[i][j] = (floatx4){0.f, 0.f, 0.f, 0.f};
      accu[i][j] = (floatx4){0.f, 0.f, 0.f, 0.f};
    }
  for (int k0 = 0; k0 < K; k0 += 64) {
#pragma unroll
    for (int s = 0; s < 4; ++s) {
      int g = (w << 2) + s;
      glds16(A + (size_t)(m0 + g * 8 + arow) * K + k0 + acol, &As[g * 512]);
    }
#pragma unroll
    for (int s = 0; s < 2; ++s) {
      int g = (w << 1) + s;
      glds16(Bg + (size_t)(n0 + g * 8 + arow) * K + k0 + acol, &Bs0[g * 512]);
      glds16(Bu + (size_t)(n0 + g * 8 + arow) * K + k0 + acol, &Bs1[g * 512]);
    }
    __syncthreads();
#pragma unroll
    for (int kc = 0; kc < 2; ++kc) {
      bf16x8 af[4], bg[2], bu[2];
#pragma unroll
      for (int mt = 0; mt < 4; ++mt)
        af[mt] = *(const bf16x8*)&As[(wm + mt * 16 + lm) * 64 + kg[kc]];
#pragma unroll
      for (int nt = 0; nt < 2; ++nt) {
        bg[nt] = *(const bf16x8*)&Bs0[(wn + nt * 16 + lm) * 64 + kg[kc]];
        bu[nt] = *(const bf16x8*)&Bs1[(wn + nt * 16 + lm) * 64 + kg[kc]];
      }
#pragma unroll
      for (int mt = 0; mt < 4; ++mt)
#pragma unroll
        for (int nt = 0; nt < 2; ++nt) {
          accg[mt][nt] = __builtin_amdgcn_mfma_f32_16x16x32_bf16(af[mt], bg[nt], accg[mt][nt], 0, 0, 0);
          accu[mt][nt] = __builtin_amdgcn_mfma_f32_16x16x32_bf16(af[mt], bu[nt], accu[mt][nt], 0, 0, 0);
        }
    }
    __syncthreads();
  }
#pragma unroll
  for (int mt = 0; mt < 4; ++mt)
#pragma unroll
    for (int nt = 0; nt < 2; ++nt)
#pragma unroll
      for (int r = 0; r < 4; ++r) {
        int row = m0 + wm + mt * 16 + lq * 4 + r;
        int col = n0 + wn + nt * 16 + lm;
        float gv = accg[mt][nt][r];
        float hv = gv / (1.f + __expf(-gv)) * accu[mt][nt][r];
        H[(size_t)row * N + col] = f2bf(hv);
      }
}

// ============ MFMA flash attention: 64-key tiles, S^T trick, split-Lc x2 ============
// 1D grid (960), group-major: all 48 blocks of one (b,kvh) K/V-slice dispatch-adjacent.
__global__ __launch_bounds__(256) void attn_kernel(const ushort* __restrict__ qb,
                                                   const ushort* __restrict__ kb,
                                                   const ushort* __restrict__ vt,
                                                   ushort* __restrict__ Op,
                                                   float* __restrict__ Ml) {
  int bid = blockIdx.x;
  int g = bid / 48, wi = bid - g * 48;
  int b = g / 5, kvh = g - b * 5;
  int hsub = wi % 3;
  int t2 = wi / 3;
  int lt = t2 & 7, sp = t2 >> 3;
  int h = kvh * 3 + hsub;
  int l0 = lt * 64;
  int kv0 = sp * 1024;
  __shared__ ushort Qs[64 * 64];
  __shared__ ushort Ks[64 * 64];
  __shared__ ushort Vs[64 * 64];
  __shared__ ushort Ps[4][16][72];
  int tid = threadIdx.x;
  int w = tid >> 6, lane = tid & 63, lm = lane & 15, lq = lane >> 4;
  int arow = lane >> 3, acol = ((lane & 7) ^ arow) << 3;
  int kg[2] = {((lq) ^ (lm & 7)) << 3, ((4 + lq) ^ (lm & 7)) << 3};
#pragma unroll
  for (int s = 0; s < 2; ++s) {
    int gg = (w << 1) + s;
    glds16(qb + (size_t)(b * LL + l0 + gg * 8 + arow) * QDIM + h * HEAD_DIM + acol, &Qs[gg * 512]);
  }
  __syncthreads();
  bf16x8 aq[2];
  {
    int qr = w * 16 + lm;
    aq[0] = *(const bf16x8*)&Qs[qr * 64 + (((lq) ^ (qr & 7)) << 3)];
    aq[1] = *(const bf16x8*)&Qs[qr * 64 + (((4 + lq) ^ (qr & 7)) << 3)];
  }
  floatx4 oacc[4];
#pragma unroll
  for (int i = 0; i < 4; ++i) oacc[i] = (floatx4){0.f, 0.f, 0.f, 0.f};
  float l_loc = 0.f;

  for (int m0 = kv0; m0 < kv0 + 1024; m0 += 64) {
#pragma unroll
    for (int s = 0; s < 2; ++s) {
      int gg = (w << 1) + s;
      glds16(kb + (size_t)(b * LC + m0 + gg * 8 + arow) * KV_DIM + kvh * HEAD_DIM + acol, &Ks[gg * 512]);
      glds16(vt + ((size_t)(b * KV_H + kvh) * 64 + gg * 8 + arow) * LC + m0 + acol, &Vs[gg * 512]);
    }
    __syncthreads();

    floatx4 sacc[4];
#pragma unroll
    for (int nt = 0; nt < 4; ++nt) sacc[nt] = (floatx4){0.f, 0.f, 0.f, 0.f};
#pragma unroll
    for (int kc = 0; kc < 2; ++kc) {
#pragma unroll
      for (int nt = 0; nt < 4; ++nt) {
        bf16x8 bk = *(const bf16x8*)&Ks[(nt * 16 + lm) * 64 + kg[kc]];
        sacc[nt] = __builtin_amdgcn_mfma_f32_16x16x32_bf16(bk, aq[kc], sacc[nt], 0, 0, 0);
      }
    }
#pragma unroll
    for (int nt = 0; nt < 4; ++nt) {
      float p0 = exp2f(sacc[nt][0]);
      float p1 = exp2f(sacc[nt][1]);
      float p2 = exp2f(sacc[nt][2]);
      float p3 = exp2f(sacc[nt][3]);
      l_loc += (p0 + p1) + (p2 + p3);
      uint2v pk = (uint2v){pk2bf(p0, p1), pk2bf(p2, p3)};
      *(uint2v*)&Ps[w][lm][nt * 16 + lq * 4] = pk;
    }
#pragma unroll
    for (int kc2 = 0; kc2 < 2; ++kc2) {
      bf16x8 ap = *(const bf16x8*)&Ps[w][lm][kc2 * 32 + lq * 8];
#pragma unroll
      for (int dt = 0; dt < 4; ++dt) {
        bf16x8 bv = *(const bf16x8*)&Vs[(dt * 16 + lm) * 64 + kg[kc2]];
        oacc[dt] = __builtin_amdgcn_mfma_f32_16x16x32_bf16(ap, bv, oacc[dt], 0, 0, 0);
      }
    }
    __syncthreads();
  }
  l_loc += __shfl_xor(l_loc, 16);
  l_loc += __shfl_xor(l_loc, 32);
#pragma unroll
  for (int r = 0; r < 4; ++r) {
    int row = l0 + w * 16 + lq * 4 + r;
    size_t base = ((size_t)sp * (BB * LL) + b * LL + row) * QDIM + h * HEAD_DIM;
#pragma unroll
    for (int dt = 0; dt < 4; ++dt) Op[base + dt * 16 + lm] = f2bf(oacc[dt][r]);
  }
  if (lq == 0) {
    int row = l0 + w * 16 + lm;
    Ml[((size_t)sp * (BB * LL) + b * LL + row) * Q_H + h] = l_loc;
  }
}

// combine two split partials -> ctx
__global__ __launch_bounds__(256) void combine_kernel(ushort* __restrict__ Op,
                                                      const float* __restrict__ Ml,
                                                      ushort* __restrict__ ctx) {
  int bl = blockIdx.x, t = threadIdx.x;
  if (t >= 240) return;
  int h = t >> 4, d4 = (t & 15) * 4;
  float la = Ml[(size_t)bl * Q_H + h];
  float lb = Ml[((size_t)(BB * LL) + bl) * Q_H + h];
  float inv = 1.f / (la + lb);
  size_t i0 = (size_t)bl * QDIM + h * HEAD_DIM + d4;
  size_t i1 = (size_t)(BB * LL) * QDIM + i0;
#pragma unroll
  for (int j = 0; j < 4; ++j) {
    float o = (bf2f(Op[i0 + j]) + bf2f(Op[i1 + j])) * inv;
    ctx[i0 + j] = f2bf(o);
  }
}

extern "C" void kernel_launch(void* const* d_in, const int* in_sizes, int n_in,
                              void* d_out, int out_size, void* d_ws, size_t ws_size,
                              hipStream_t stream) {
  const float* x      = (const float*)d_in[0];
  const float* text_k = (const float*)d_in[1];
  const float* text_v = (const float*)d_in[2];
  const float* ln1_w  = (const float*)d_in[3];
  const float* ln2_w  = (const float*)d_in[4];
  const float* wq     = (const float*)d_in[5];
  const float* wk     = (const float*)d_in[6];
  const float* wv     = (const float*)d_in[7];
  const float* wo     = (const float*)d_in[8];
  const float* w_gate = (const float*)d_in[9];
  const float* w_up   = (const float*)d_in[10];
  const float* w_down = (const float*)d_in[11];
  float* out = (float*)d_out;
  char* base = (char*)d_ws;

  const int BL = BB * LL;   // 2048
  const int BLC = BB * LC;  // 8192

  ushort* xnorm = (ushort*)(base + 0);          // 3,145,728
  ushort* wqt   = (ushort*)(base + 3145728);    // 1,474,560
  ushort* wkt   = (ushort*)(base + 4620288);    //   204,800
  ushort* wvt   = (ushort*)(base + 4825088);    //   204,800
  ushort* wot   = (ushort*)(base + 5029888);    // 1,474,560
  ushort* wgt   = (ushort*)(base + 6504448);    // 3,145,728
  ushort* wut   = (ushort*)(base + 9650176);    // 3,145,728
  ushort* wdt   = (ushort*)(base + 12795904);   // 3,145,728
  ushort* kbuf  = (ushort*)(base + 15941632);   // 5,242,880
  ushort* vtb   = (ushort*)(base + 21184512);   // 5,242,880
  float*  x2    = (float*) (base + 26427392);   // 6,291,456
  ushort* qb    = (ushort*)(base + 32718848);   // 3,932,160
  float*  Ml    = (float*) (base + 36651008);   //   245,760 (+pad)
  ushort* tkb   = (ushort*)(base + 37142528);   // 5,242,880 (bf16 text_k)
  ushort* tvb   = (ushort*)(base + 42385408);   // 5,242,880 (bf16 text_v)
  char* SCR = base + 47628288;
  ushort* Op    = (ushort*)SCR;                 // 2 x 3,932,160
  ushort* ctxb  = (ushort*)SCR;                 // combine out, in-place over Op0
  ushort* gbuf  = (ushort*)(base + 15941632);   // alias kbuf+vtb (dead after attn)

  TD7 ds;
  ds.d[0] = {wq,     wqt, EMBD,    QDIM,    QDIM / 64,    0};
  ds.d[1] = {wk,     wkt, KV_DIM,  KV_DIM,  KV_DIM / 64,  180};
  ds.d[2] = {wv,     wvt, KV_DIM,  KV_DIM,  KV_DIM / 64,  205};
  ds.d[3] = {wo,     wot, QDIM,    EMBD,    EMBD / 64,    230};
  ds.d[4] = {w_gate, wgt, EMBD,    FFN_HID, FFN_HID / 64, 410};
  ds.d[5] = {w_up,   wut, EMBD,    FFN_HID, FFN_HID / 64, 794};
  ds.d[6] = {w_down, wdt, FFN_HID, EMBD,    EMBD / 64,    1178};
  const int ntrans = 1178 + (EMBD / 64) * (FFN_HID / 64);  // 1562
  transpose_all<<<ntrans, 256, 0, stream>>>(ds, ntrans);
  rmsnorm_kernel<<<BL, 256, 0, stream>>>(x, ln1_w, xnorm);
  conv_f2b<<<(2 * BLC * KV_DIM / 4) / 256, 256, 0, stream>>>(text_k, text_v, tkb, tvb, BLC * KV_DIM / 4);

  // k/v projections, 128-tile; V written pre-transposed (no separate transpose_v)
  gemm_kv128<<<dim3(KV_DIM / 64, BLC / 128, 2), 256, 0, stream>>>(tkb, tvb, wkt, wvt, kbuf, vtb, BLC, KV_DIM, KV_DIM);

  // q projection + fused rope
  gemm_q_rope<<<dim3(QDIM / 64, BL / 128), 256, 0, stream>>>(xnorm, wqt, qb, BL, QDIM, EMBD);

  // attention (group-major 1D grid) + combine
  attn_kernel<<<960, 256, 0, stream>>>(qb, kbuf, vtb, Op, Ml);
  combine_kernel<<<BL, 256, 0, stream>>>(Op, Ml, ctxb);

  // x2 = ctx @ wo + x  (direct store, fused residual)
  gemm64<1><<<dim3(EMBD / 64, BL / 64), 256, 0, stream>>>(ctxb, wot, x, x2, BL, EMBD, QDIM);

  rmsnorm_kernel<<<BL, 256, 0, stream>>>(x2, ln2_w, xnorm);
  gemm_gateup<<<dim3(FFN_HID / 64, BL / 128), 256, 0, stream>>>(xnorm, wgt, wut, gbuf, BL, FFN_HID, EMBD);
  // out = h @ w_down + x2  (direct store, fused residual)
  gemm64<1><<<dim3(EMBD / 64, BL / 64), 256, 0, stream>>>(gbuf, wdt, x2, out, BL, EMBD, FFN_HID);
}

// Round 11
// 237.251 us; speedup vs baseline: 1.0756x; 1.0187x over previous
//
#include <hip/hip_runtime.h>
#include <hip/hip_bf16.h>
#include <math.h>

#define EMBD 768
#define FFN_HID 2048
#define HEAD_DIM 64
#define KV_H 5
#define KV_DIM 320
#define Q_H 15
#define QDIM (Q_H * HEAD_DIM) /* 960 */
#define BB 4
#define LL 512
#define LC 2048
#define EPSV 1.1920929e-07f

typedef __attribute__((ext_vector_type(8))) __bf16 bf16x8;
typedef __attribute__((ext_vector_type(2))) __bf16 bf16x2;
typedef __attribute__((ext_vector_type(8))) short short8;
typedef __attribute__((ext_vector_type(4))) float floatx4;
typedef __attribute__((ext_vector_type(2))) unsigned uint2v;
typedef unsigned short ushort;

// 0.125 (1/sqrt(64)) * log2(e), folded into q at projection time
#define RSCALE 0.18033688011112042f

__device__ inline ushort f2bf(float f) {
  union { float f; unsigned u; } c; c.f = f;
  return (ushort)((c.u + 0x8000u) >> 16);
}
__device__ inline float bf2f(ushort s) {
  union { unsigned u; float f; } c; c.u = ((unsigned)s) << 16;
  return c.f;
}
#if __has_builtin(__builtin_amdgcn_cvt_pk_bf16_f32)
__device__ inline unsigned pk2bf(float a, float b) {
  union { bf16x2 v; unsigned u; } c;
  c.v = __builtin_amdgcn_cvt_pk_bf16_f32(a, b);
  return c.u;
}
#else
__device__ inline unsigned pk2bf(float a, float b) {
  union { float f; unsigned u; } x, y; x.f = a; y.f = b;
  return ((x.u + 0x8000u) >> 16) | ((y.u + 0x8000u) & 0xffff0000u);
}
#endif

__device__ __forceinline__ void glds16(const ushort* g, ushort* l) {
  __builtin_amdgcn_global_load_lds(
      (const __attribute__((address_space(1))) unsigned int*)g,
      (__attribute__((address_space(3))) unsigned int*)l, 16, 0, 0);
}

// ---------------- RMSNorm fp32 in -> bf16 out (standalone, for x2) ----------------
__global__ __launch_bounds__(256) void rmsnorm_kernel(const float* __restrict__ x,
                                                      const float* __restrict__ w,
                                                      ushort* __restrict__ out) {
  int row = blockIdx.x;
  const float* xr = x + (size_t)row * EMBD;
  ushort* orow = out + (size_t)row * EMBD;
  int tid = threadIdx.x;
  float ss = 0.f;
  for (int i = tid; i < EMBD; i += 256) { float v = xr[i]; ss += v * v; }
  for (int off = 32; off > 0; off >>= 1) ss += __shfl_down(ss, off, 64);
  __shared__ float sred[4];
  if ((tid & 63) == 0) sred[tid >> 6] = ss;
  __syncthreads();
  float tot = sred[0] + sred[1] + sred[2] + sred[3];
  float scale = rsqrtf(tot * (1.0f / EMBD) + EPSV);
  for (int i = tid; i < EMBD; i += 256) orow[i] = f2bf(xr[i] * scale * w[i]);
}

// ---------------- mega prep: transposes + f2b converts + rmsnorm1, one dispatch ----------------
// mode 0: transpose fp32 W[K][N] -> bf16 Wt[N][K] (per 64x64 tile)
// mode 1: fp32 -> bf16 convert, 1024 floats per block
// mode 2: rmsnorm row (aux = ln weight), one row per block
struct MD { const void* src; void* dst; const float* aux; int K; int N; int nx; int base; int mode; };
struct MD10 { MD d[10]; };

__global__ __launch_bounds__(256) void mega_prep(MD10 ds) {
  int bid = blockIdx.x;
  int sel = 0;
#pragma unroll
  for (int j = 1; j < 10; ++j) sel = (bid >= ds.d[j].base) ? j : sel;
  MD t = ds.d[sel];
  int rel = bid - t.base;
  int tid = threadIdx.x;
  if (t.mode == 1) {  // convert
    int i = rel * 256 + tid;
    float4 f = *(const float4*)((const float*)t.src + (size_t)i * 4);
    ushort* o = (ushort*)t.dst + (size_t)i * 4;
    o[0] = f2bf(f.x); o[1] = f2bf(f.y); o[2] = f2bf(f.z); o[3] = f2bf(f.w);
    return;
  }
  if (t.mode == 2) {  // rmsnorm row
    const float* xr = (const float*)t.src + (size_t)rel * EMBD;
    ushort* orow = (ushort*)t.dst + (size_t)rel * EMBD;
    float ss = 0.f;
    for (int i = tid; i < EMBD; i += 256) { float v = xr[i]; ss += v * v; }
    for (int off = 32; off > 0; off >>= 1) ss += __shfl_down(ss, off, 64);
    __shared__ float sred[4];
    if ((tid & 63) == 0) sred[tid >> 6] = ss;
    __syncthreads();
    float tot = sred[0] + sred[1] + sred[2] + sred[3];
    float scale = rsqrtf(tot * (1.0f / EMBD) + EPSV);
    for (int i = tid; i < EMBD; i += 256) orow[i] = f2bf(xr[i] * scale * t.aux[i]);
    return;
  }
  // mode 0: weight transpose tile
  int bx = rel % t.nx, by = rel / t.nx;
  int k0 = by * 64, n0 = bx * 64;
  __shared__ ushort T[64][72];
  int r = tid >> 2, cb = (tid & 3) * 16;
#pragma unroll
  for (int i = 0; i < 16; i += 4) {
    float4 f = *(const float4*)((const float*)t.src + (size_t)(k0 + r) * t.N + n0 + cb + i);
    T[r][cb + i + 0] = f2bf(f.x); T[r][cb + i + 1] = f2bf(f.y);
    T[r][cb + i + 2] = f2bf(f.z); T[r][cb + i + 3] = f2bf(f.w);
  }
  __syncthreads();
#pragma unroll
  for (int i = 0; i < 2; ++i) {
    short8 v;
#pragma unroll
    for (int j = 0; j < 8; ++j) v[j] = (short)T[cb + i * 8 + j][r];
    *(short8*)((ushort*)t.dst + (size_t)(n0 + r) * t.K + k0 + cb + i * 8) = v;
  }
}

// ============ 64x64-tile bf16 GEMM (4 waves 2x2), glds + swizzle ============
// OM: 1 = f32 out + residual Rf, 2 = bf16 out
template <int OM>
__global__ __launch_bounds__(256) void gemm64(const ushort* __restrict__ A,
                                              const ushort* __restrict__ Bt,
                                              const float* __restrict__ Rf,
                                              void* __restrict__ Cout,
                                              int M, int N, int K) {
  __shared__ ushort As[64 * 64];
  __shared__ ushort Bs[64 * 64];
  int tid = threadIdx.x;
  int w = tid >> 6, lane = tid & 63;
  int lm = lane & 15, lq = lane >> 4;
  int m0 = blockIdx.y * 64, n0 = blockIdx.x * 64;
  int wm = (w & 1) * 32, wn = (w >> 1) * 32;
  int arow = lane >> 3, acol = ((lane & 7) ^ arow) << 3;
  int kg[2] = {((lq) ^ (lm & 7)) << 3, ((4 + lq) ^ (lm & 7)) << 3};
  floatx4 acc[2][2];
#pragma unroll
  for (int i = 0; i < 2; ++i)
#pragma unroll
    for (int j = 0; j < 2; ++j) acc[i][j] = (floatx4){0.f, 0.f, 0.f, 0.f};
  for (int k0 = 0; k0 < K; k0 += 64) {
#pragma unroll
    for (int s = 0; s < 2; ++s) {
      int g = (w << 1) + s;
      glds16(A + (size_t)(m0 + g * 8 + arow) * K + k0 + acol, &As[g * 512]);
      glds16(Bt + (size_t)(n0 + g * 8 + arow) * K + k0 + acol, &Bs[g * 512]);
    }
    __syncthreads();
#pragma unroll
    for (int kc = 0; kc < 2; ++kc) {
      bf16x8 af[2], bf[2];
#pragma unroll
      for (int mt = 0; mt < 2; ++mt)
        af[mt] = *(const bf16x8*)&As[(wm + mt * 16 + lm) * 64 + kg[kc]];
#pragma unroll
      for (int nt = 0; nt < 2; ++nt)
        bf[nt] = *(const bf16x8*)&Bs[(wn + nt * 16 + lm) * 64 + kg[kc]];
#pragma unroll
      for (int mt = 0; mt < 2; ++mt)
#pragma unroll
        for (int nt = 0; nt < 2; ++nt)
          acc[mt][nt] = __builtin_amdgcn_mfma_f32_16x16x32_bf16(af[mt], bf[nt], acc[mt][nt], 0, 0, 0);
    }
    __syncthreads();
  }
#pragma unroll
  for (int mt = 0; mt < 2; ++mt)
#pragma unroll
    for (int nt = 0; nt < 2; ++nt)
#pragma unroll
      for (int r = 0; r < 4; ++r) {
        int row = m0 + wm + mt * 16 + lq * 4 + r;
        int col = n0 + wn + nt * 16 + lm;
        size_t idx = (size_t)row * N + col;
        float vv = acc[mt][nt][r];
        if (OM == 1) ((float*)Cout)[idx] = vv + Rf[idx];
        if (OM == 2) ((ushort*)Cout)[idx] = f2bf(vv);
      }
}

// ---- z-merged k/v projection, 128x64 tiles; V written pre-transposed ----
__global__ __launch_bounds__(256) void gemm_kv128(const ushort* __restrict__ Ak,
                                                  const ushort* __restrict__ Av,
                                                  const ushort* __restrict__ Btk,
                                                  const ushort* __restrict__ Btv,
                                                  ushort* __restrict__ Ck,
                                                  ushort* __restrict__ Vt,
                                                  int M, int N, int K) {
  const ushort* A = blockIdx.z ? Av : Ak;
  const ushort* Bt = blockIdx.z ? Btv : Btk;
  __shared__ ushort As[128 * 64];
  __shared__ ushort Bs[64 * 64];
  int tid = threadIdx.x;
  int w = tid >> 6, lane = tid & 63;
  int lm = lane & 15, lq = lane >> 4;
  int m0 = blockIdx.y * 128, n0 = blockIdx.x * 64;
  int wm = (w & 1) * 64, wn = (w >> 1) * 32;
  int arow = lane >> 3, acol = ((lane & 7) ^ arow) << 3;
  int kg[2] = {((lq) ^ (lm & 7)) << 3, ((4 + lq) ^ (lm & 7)) << 3};
  floatx4 acc[4][2];
#pragma unroll
  for (int i = 0; i < 4; ++i)
#pragma unroll
    for (int j = 0; j < 2; ++j) acc[i][j] = (floatx4){0.f, 0.f, 0.f, 0.f};
  for (int k0 = 0; k0 < K; k0 += 64) {
#pragma unroll
    for (int s = 0; s < 4; ++s) {
      int g = (w << 2) + s;
      glds16(A + (size_t)(m0 + g * 8 + arow) * K + k0 + acol, &As[g * 512]);
    }
#pragma unroll
    for (int s = 0; s < 2; ++s) {
      int g = (w << 1) + s;
      glds16(Bt + (size_t)(n0 + g * 8 + arow) * K + k0 + acol, &Bs[g * 512]);
    }
    __syncthreads();
#pragma unroll
    for (int kc = 0; kc < 2; ++kc) {
      bf16x8 af[4], bf[2];
#pragma unroll
      for (int mt = 0; mt < 4; ++mt)
        af[mt] = *(const bf16x8*)&As[(wm + mt * 16 + lm) * 64 + kg[kc]];
#pragma unroll
      for (int nt = 0; nt < 2; ++nt)
        bf[nt] = *(const bf16x8*)&Bs[(wn + nt * 16 + lm) * 64 + kg[kc]];
#pragma unroll
      for (int mt = 0; mt < 4; ++mt)
#pragma unroll
        for (int nt = 0; nt < 2; ++nt)
          acc[mt][nt] = __builtin_amdgcn_mfma_f32_16x16x32_bf16(af[mt], bf[nt], acc[mt][nt], 0, 0, 0);
    }
    __syncthreads();
  }
  if (blockIdx.z == 0) {  // K: row-major [token][KV_DIM]
#pragma unroll
    for (int mt = 0; mt < 4; ++mt)
#pragma unroll
      for (int nt = 0; nt < 2; ++nt)
#pragma unroll
        for (int r = 0; r < 4; ++r) {
          int row = m0 + wm + mt * 16 + lq * 4 + r;
          int col = n0 + wn + nt * 16 + lm;
          Ck[(size_t)row * N + col] = f2bf(acc[mt][nt][r]);
        }
  } else {  // V: write transposed vt[(b*5+kvh)*64+d][token], 4 tokens packed
    int kvh = n0 >> 6;
#pragma unroll
    for (int mt = 0; mt < 4; ++mt)
#pragma unroll
      for (int nt = 0; nt < 2; ++nt) {
        int d = wn + nt * 16 + lm;
        int grow = m0 + wm + mt * 16 + lq * 4;  // token base, 4-aligned
        int b = grow >> 11;
        int tok = grow & (LC - 1);
        size_t a = ((size_t)(b * KV_H + kvh) * 64 + d) * LC + tok;
        uint2v pk = (uint2v){pk2bf(acc[mt][nt][0], acc[mt][nt][1]),
                             pk2bf(acc[mt][nt][2], acc[mt][nt][3])};
        *(uint2v*)&Vt[a] = pk;
      }
  }
}

// ---- q projection, 128x64 tiles, fused RoPE + softmax prescale ----
__global__ __launch_bounds__(256) void gemm_q_rope(const ushort* __restrict__ A,
                                                   const ushort* __restrict__ Bt,
                                                   ushort* __restrict__ Q,
                                                   int M, int N, int K) {
  __shared__ ushort As[128 * 64];
  __shared__ ushort Bs[64 * 64];
  int tid = threadIdx.x;
  int w = tid >> 6, lane = tid & 63;
  int lm = lane & 15, lq = lane >> 4;
  int m0 = blockIdx.y * 128, n0 = blockIdx.x * 64;
  int wm = (w & 1) * 64, wn = (w >> 1) * 16;  // cols wn+lm and +32
  int arow = lane >> 3, acol = ((lane & 7) ^ arow) << 3;
  int kg[2] = {((lq) ^ (lm & 7)) << 3, ((4 + lq) ^ (lm & 7)) << 3};
  floatx4 acc[4][2];
#pragma unroll
  for (int i = 0; i < 4; ++i)
#pragma unroll
    for (int j = 0; j < 2; ++j) acc[i][j] = (floatx4){0.f, 0.f, 0.f, 0.f};
  for (int k0 = 0; k0 < K; k0 += 64) {
#pragma unroll
    for (int s = 0; s < 4; ++s) {
      int g = (w << 2) + s;
      glds16(A + (size_t)(m0 + g * 8 + arow) * K + k0 + acol, &As[g * 512]);
    }
#pragma unroll
    for (int s = 0; s < 2; ++s) {
      int g = (w << 1) + s;
      glds16(Bt + (size_t)(n0 + g * 8 + arow) * K + k0 + acol, &Bs[g * 512]);
    }
    __syncthreads();
#pragma unroll
    for (int kc = 0; kc < 2; ++kc) {
      bf16x8 af[4], bf[2];
#pragma unroll
      for (int mt = 0; mt < 4; ++mt)
        af[mt] = *(const bf16x8*)&As[(wm + mt * 16 + lm) * 64 + kg[kc]];
#pragma unroll
      for (int nt = 0; nt < 2; ++nt) {
        int br = wn + nt * 32 + lm;
        bf[nt] = *(const bf16x8*)&Bs[br * 64 + (((kc * 4 + lq) ^ (br & 7)) << 3)];
      }
#pragma unroll
      for (int mt = 0; mt < 4; ++mt)
#pragma unroll
        for (int nt = 0; nt < 2; ++nt)
          acc[mt][nt] = __builtin_amdgcn_mfma_f32_16x16x32_bf16(af[mt], bf[nt], acc[mt][nt], 0, 0, 0);
    }
    __syncthreads();
  }
  int d = wn + lm;  // 0..31
  float invts = exp2f(-(float)d * 0.4152410118609203f);  // 10000^(-d/32)
#pragma unroll
  for (int mt = 0; mt < 4; ++mt)
#pragma unroll
    for (int r = 0; r < 4; ++r) {
      int row = m0 + wm + mt * 16 + lq * 4 + r;
      int l = row & (LL - 1);
      float th = (float)l * invts;
      float s, c;
      __sincosf(th, &s, &c);
      float q1 = acc[mt][0][r], q2 = acc[mt][1][r];
      size_t base = (size_t)row * N + n0 + d;
      Q[base] = f2bf((q1 * c - q2 * s) * RSCALE);
      Q[base + 32] = f2bf((q2 * c + q1 * s) * RSCALE);
    }
}

// ---- fused gate+up: 128x64 tile, silu(g)*u epilogue ----
__global__ __launch_bounds__(256) void gemm_gateup(const ushort* __restrict__ A,
                                                   const ushort* __restrict__ Bg,
                                                   const ushort* __restrict__ Bu,
                                                   ushort* __restrict__ H,
                                                   int M, int N, int K) {
  __shared__ ushort As[128 * 64];
  __shared__ ushort Bs0[64 * 64];
  __shared__ ushort Bs1[64 * 64];
  int tid = threadIdx.x;
  int w = tid >> 6, lane = tid & 63;
  int lm = lane & 15, lq = lane >> 4;
  int m0 = blockIdx.y * 128, n0 = blockIdx.x * 64;
  int wm = (w & 1) * 64, wn = (w >> 1) * 32;
  int arow = lane >> 3, acol = ((lane & 7) ^ arow) << 3;
  int kg[2] = {((lq) ^ (lm & 7)) << 3, ((4 + lq) ^ (lm & 7)) << 3};
  floatx4 accg[4][2], accu[4][2];
#pragma unroll
  for (int i = 0; i < 4; ++i)
#pragma unroll
    for (int j = 0; j < 2; ++j) {
      accg[i][j] = (floatx4){0.f, 0.f, 0.f, 0.f};
      accu[i][j] = (floatx4){0.f, 0.f, 0.f, 0.f};
    }
  for (int k0 = 0; k0 < K; k0 += 64) {
#pragma unroll
    for (int s = 0; s < 4; ++s) {
      int g = (w << 2) + s;
      glds16(A + (size_t)(m0 + g * 8 + arow) * K + k0 + acol, &As[g * 512]);
    }
#pragma unroll
    for (int s = 0; s < 2; ++s) {
      int g = (w << 1) + s;
      glds16(Bg + (size_t)(n0 + g * 8 + arow) * K + k0 + acol, &Bs0[g * 512]);
      glds16(Bu + (size_t)(n0 + g * 8 + arow) * K + k0 + acol, &Bs1[g * 512]);
    }
    __syncthreads();
#pragma unroll
    for (int kc = 0; kc < 2; ++kc) {
      bf16x8 af[4], bg[2], bu[2];
#pragma unroll
      for (int mt = 0; mt < 4; ++mt)
        af[mt] = *(const bf16x8*)&As[(wm + mt * 16 + lm) * 64 + kg[kc]];
#pragma unroll
      for (int nt = 0; nt < 2; ++nt) {
        bg[nt] = *(const bf16x8*)&Bs0[(wn + nt * 16 + lm) * 64 + kg[kc]];
        bu[nt] = *(const bf16x8*)&Bs1[(wn + nt * 16 + lm) * 64 + kg[kc]];
      }
#pragma unroll
      for (int mt = 0; mt < 4; ++mt)
#pragma unroll
        for (int nt = 0; nt < 2; ++nt) {
          accg[mt][nt] = __builtin_amdgcn_mfma_f32_16x16x32_bf16(af[mt], bg[nt], accg[mt][nt], 0, 0, 0);
          accu[mt][nt] = __builtin_amdgcn_mfma_f32_16x16x32_bf16(af[mt], bu[nt], accu[mt][nt], 0, 0, 0);
        }
    }
    __syncthreads();
  }
#pragma unroll
  for (int mt = 0; mt < 4; ++mt)
#pragma unroll
    for (int nt = 0; nt < 2; ++nt)
#pragma unroll
      for (int r = 0; r < 4; ++r) {
        int row = m0 + wm + mt * 16 + lq * 4 + r;
        int col = n0 + wn + nt * 16 + lm;
        float gv = accg[mt][nt][r];
        float hv = gv / (1.f + __expf(-gv)) * accu[mt][nt][r];
        H[(size_t)row * N + col] = f2bf(hv);
      }
}

// ============ MFMA flash attention: 64-key tiles, S^T trick, ones-MFMA l-sum ============
__global__ __launch_bounds__(256) void attn_kernel(const ushort* __restrict__ qb,
                                                   const ushort* __restrict__ kb,
                                                   const ushort* __restrict__ vt,
                                                   ushort* __restrict__ Op,
                                                   float* __restrict__ Ml) {
  int bid = blockIdx.x;
  int g = bid / 48, wi = bid - g * 48;
  int b = g / 5, kvh = g - b * 5;
  int hsub = wi % 3;
  int t2 = wi / 3;
  int lt = t2 & 7, sp = t2 >> 3;
  int h = kvh * 3 + hsub;
  int l0 = lt * 64;
  int kv0 = sp * 1024;
  __shared__ ushort Qs[64 * 64];
  __shared__ ushort Ks[64 * 64];
  __shared__ ushort Vs[64 * 64];
  __shared__ ushort Ps[4][16][72];
  int tid = threadIdx.x;
  int w = tid >> 6, lane = tid & 63, lm = lane & 15, lq = lane >> 4;
  int arow = lane >> 3, acol = ((lane & 7) ^ arow) << 3;
  int kg[2] = {((lq) ^ (lm & 7)) << 3, ((4 + lq) ^ (lm & 7)) << 3};
#pragma unroll
  for (int s = 0; s < 2; ++s) {
    int gg = (w << 1) + s;
    glds16(qb + (size_t)(b * LL + l0 + gg * 8 + arow) * QDIM + h * HEAD_DIM + acol, &Qs[gg * 512]);
  }
  __syncthreads();
  bf16x8 aq[2];
  {
    int qr = w * 16 + lm;
    aq[0] = *(const bf16x8*)&Qs[qr * 64 + (((lq) ^ (qr & 7)) << 3)];
    aq[1] = *(const bf16x8*)&Qs[qr * 64 + (((4 + lq) ^ (qr & 7)) << 3)];
  }
  // all-ones B fragment for the l-sum MFMA (bf16 1.0 = 0x3F80)
  bf16x8 bones;
  {
    short8 o = {0x3F80, 0x3F80, 0x3F80, 0x3F80, 0x3F80, 0x3F80, 0x3F80, 0x3F80};
    bones = *(bf16x8*)&o;
  }
  floatx4 oacc[4];
#pragma unroll
  for (int i = 0; i < 4; ++i) oacc[i] = (floatx4){0.f, 0.f, 0.f, 0.f};
  floatx4 lacc = (floatx4){0.f, 0.f, 0.f, 0.f};  // l per q-row via P @ ones

  for (int m0 = kv0; m0 < kv0 + 1024; m0 += 64) {
#pragma unroll
    for (int s = 0; s < 2; ++s) {
      int gg = (w << 1) + s;
      glds16(kb + (size_t)(b * LC + m0 + gg * 8 + arow) * KV_DIM + kvh * HEAD_DIM + acol, &Ks[gg * 512]);
      glds16(vt + ((size_t)(b * KV_H + kvh) * 64 + gg * 8 + arow) * LC + m0 + acol, &Vs[gg * 512]);
    }
    __syncthreads();

    // S^T = K @ Q^T: sacc[nt] rows=keys nt*16+lq*4+r, col=q=lm
    floatx4 sacc[4];
#pragma unroll
    for (int nt = 0; nt < 4; ++nt) sacc[nt] = (floatx4){0.f, 0.f, 0.f, 0.f};
#pragma unroll
    for (int kc = 0; kc < 2; ++kc) {
#pragma unroll
      for (int nt = 0; nt < 4; ++nt) {
        bf16x8 bk = *(const bf16x8*)&Ks[(nt * 16 + lm) * 64 + kg[kc]];
        sacc[nt] = __builtin_amdgcn_mfma_f32_16x16x32_bf16(bk, aq[kc], sacc[nt], 0, 0, 0);
      }
    }
    // softmax numerators (Q prescaled by 0.125*log2e): p = 2^s, packed bf16 store
#pragma unroll
    for (int nt = 0; nt < 4; ++nt) {
      float p0 = exp2f(sacc[nt][0]);
      float p1 = exp2f(sacc[nt][1]);
      float p2 = exp2f(sacc[nt][2]);
      float p3 = exp2f(sacc[nt][3]);
      uint2v pk = (uint2v){pk2bf(p0, p1), pk2bf(p2, p3)};
      *(uint2v*)&Ps[w][lm][nt * 16 + lq * 4] = pk;
    }
    // PV (+ l-sum via ones column): A = P[q][key], B = V^T / ones
#pragma unroll
    for (int kc2 = 0; kc2 < 2; ++kc2) {
      bf16x8 ap = *(const bf16x8*)&Ps[w][lm][kc2 * 32 + lq * 8];
#pragma unroll
      for (int dt = 0; dt < 4; ++dt) {
        bf16x8 bv = *(const bf16x8*)&Vs[(dt * 16 + lm) * 64 + kg[kc2]];
        oacc[dt] = __builtin_amdgcn_mfma_f32_16x16x32_bf16(ap, bv, oacc[dt], 0, 0, 0);
      }
      lacc = __builtin_amdgcn_mfma_f32_16x16x32_bf16(ap, bones, lacc, 0, 0, 0);
    }
    __syncthreads();
  }
  // lacc[r] = softmax denom for q-row lq*4+r (identical across lm lanes); no shuffles
#pragma unroll
  for (int r = 0; r < 4; ++r) {
    int row = l0 + w * 16 + lq * 4 + r;
    size_t base = ((size_t)sp * (BB * LL) + b * LL + row) * QDIM + h * HEAD_DIM;
#pragma unroll
    for (int dt = 0; dt < 4; ++dt) Op[base + dt * 16 + lm] = f2bf(oacc[dt][r]);
    if (lm == 0) Ml[((size_t)sp * (BB * LL) + b * LL + row) * Q_H + h] = lacc[r];
  }
}

// combine two split partials -> ctx
__global__ __launch_bounds__(256) void combine_kernel(ushort* __restrict__ Op,
                                                      const float* __restrict__ Ml,
                                                      ushort* __restrict__ ctx) {
  int bl = blockIdx.x, t = threadIdx.x;
  if (t >= 240) return;
  int h = t >> 4, d4 = (t & 15) * 4;
  float la = Ml[(size_t)bl * Q_H + h];
  float lb = Ml[((size_t)(BB * LL) + bl) * Q_H + h];
  float inv = 1.f / (la + lb);
  size_t i0 = (size_t)bl * QDIM + h * HEAD_DIM + d4;
  size_t i1 = (size_t)(BB * LL) * QDIM + i0;
#pragma unroll
  for (int j = 0; j < 4; ++j) {
    float o = (bf2f(Op[i0 + j]) + bf2f(Op[i1 + j])) * inv;
    ctx[i0 + j] = f2bf(o);
  }
}

extern "C" void kernel_launch(void* const* d_in, const int* in_sizes, int n_in,
                              void* d_out, int out_size, void* d_ws, size_t ws_size,
                              hipStream_t stream) {
  const float* x      = (const float*)d_in[0];
  const float* text_k = (const float*)d_in[1];
  const float* text_v = (const float*)d_in[2];
  const float* ln1_w  = (const float*)d_in[3];
  const float* ln2_w  = (const float*)d_in[4];
  const float* wq     = (const float*)d_in[5];
  const float* wk     = (const float*)d_in[6];
  const float* wv     = (const float*)d_in[7];
  const float* wo     = (const float*)d_in[8];
  const float* w_gate = (const float*)d_in[9];
  const float* w_up   = (const float*)d_in[10];
  const float* w_down = (const float*)d_in[11];
  float* out = (float*)d_out;
  char* base = (char*)d_ws;

  const int BL = BB * LL;   // 2048
  const int BLC = BB * LC;  // 8192

  ushort* xnorm = (ushort*)(base + 0);          // 3,145,728
  ushort* wqt   = (ushort*)(base + 3145728);    // 1,474,560
  ushort* wkt   = (ushort*)(base + 4620288);    //   204,800
  ushort* wvt   = (ushort*)(base + 4825088);    //   204,800
  ushort* wot   = (ushort*)(base + 5029888);    // 1,474,560
  ushort* wgt   = (ushort*)(base + 6504448);    // 3,145,728
  ushort* wut   = (ushort*)(base + 9650176);    // 3,145,728
  ushort* wdt   = (ushort*)(base + 12795904);   // 3,145,728
  ushort* kbuf  = (ushort*)(base + 15941632);   // 5,242,880
  ushort* vtb   = (ushort*)(base + 21184512);   // 5,242,880
  float*  x2    = (float*) (base + 26427392);   // 6,291,456
  ushort* qb    = (ushort*)(base + 32718848);   // 3,932,160
  float*  Ml    = (float*) (base + 36651008);   //   245,760 (+pad)
  ushort* tkb   = (ushort*)(base + 37142528);   // 5,242,880 (bf16 text_k)
  ushort* tvb   = (ushort*)(base + 42385408);   // 5,242,880 (bf16 text_v)
  char* SCR = base + 47628288;
  ushort* Op    = (ushort*)SCR;                 // 2 x 3,932,160
  ushort* ctxb  = (ushort*)SCR;                 // combine out, in-place over Op0
  ushort* gbuf  = (ushort*)(base + 15941632);   // alias kbuf+vtb (dead after attn)

  // mega prep: 7 transposes + 2 converts + rmsnorm1, one dispatch
  MD10 ds;
  const int NKV4 = BLC * KV_DIM / 1024;  // 2560 conv blocks per tensor
  ds.d[0] = {wq,     wqt,   nullptr, EMBD,    QDIM,    QDIM / 64,    0,    0};
  ds.d[1] = {wk,     wkt,   nullptr, KV_DIM,  KV_DIM,  KV_DIM / 64,  180,  0};
  ds.d[2] = {wv,     wvt,   nullptr, KV_DIM,  KV_DIM,  KV_DIM / 64,  205,  0};
  ds.d[3] = {wo,     wot,   nullptr, QDIM,    EMBD,    EMBD / 64,    230,  0};
  ds.d[4] = {w_gate, wgt,   nullptr, EMBD,    FFN_HID, FFN_HID / 64, 410,  0};
  ds.d[5] = {w_up,   wut,   nullptr, EMBD,    FFN_HID, FFN_HID / 64, 794,  0};
  ds.d[6] = {w_down, wdt,   nullptr, FFN_HID, EMBD,    EMBD / 64,    1178, 0};
  ds.d[7] = {text_k, tkb,   nullptr, 0, 0, 0, 1562, 1};
  ds.d[8] = {text_v, tvb,   nullptr, 0, 0, 0, 1562 + NKV4, 1};
  ds.d[9] = {x,      xnorm, ln1_w,   0, 0, 0, 1562 + 2 * NKV4, 2};
  const int nmega = 1562 + 2 * NKV4 + BL;  // 1562 + 5120 + 2048 = 8730
  mega_prep<<<nmega, 256, 0, stream>>>(ds);

  // k/v projections, 128-tile; V written pre-transposed
  gemm_kv128<<<dim3(KV_DIM / 64, BLC / 128, 2), 256, 0, stream>>>(tkb, tvb, wkt, wvt, kbuf, vtb, BLC, KV_DIM, KV_DIM);

  // q projection + fused rope
  gemm_q_rope<<<dim3(QDIM / 64, BL / 128), 256, 0, stream>>>(xnorm, wqt, qb, BL, QDIM, EMBD);

  // attention (group-major 1D grid) + combine
  attn_kernel<<<960, 256, 0, stream>>>(qb, kbuf, vtb, Op, Ml);
  combine_kernel<<<BL, 256, 0, stream>>>(Op, Ml, ctxb);

  // x2 = ctx @ wo + x  (direct store, fused residual)
  gemm64<1><<<dim3(EMBD / 64, BL / 64), 256, 0, stream>>>(ctxb, wot, x, x2, BL, EMBD, QDIM);

  rmsnorm_kernel<<<BL, 256, 0, stream>>>(x2, ln2_w, xnorm);
  gemm_gateup<<<dim3(FFN_HID / 64, BL / 128), 256, 0, stream>>>(xnorm, wgt, wut, gbuf, BL, FFN_HID, EMBD);
  // out = h @ w_down + x2  (direct store, fused residual)
  gemm64<1><<<dim3(EMBD / 64, BL / 64), 256, 0, stream>>>(gbuf, wdt, x2, out, BL, EMBD, FFN_HID);
}